// Round 8
// baseline (533.487 us; speedup 1.0000x reference)
//
#include <hip/hip_runtime.h>
#include <hip/hip_bf16.h>
#include <cstdint>
#include <cstddef>

typedef __hip_bfloat16 bf16;

#define N_NODES  50000
#define N_EDGES  150000
#define N_GRAPHS 1024
#define IN_DIM   78
#define K1P      128                   /* IN_DIM padded to mult of 64 (BK) */
#define OUT_DIM  64
#define HEADS    10
#define HID      640
#define NEG_SLOPE 0.2f
#define SCB      ((N_NODES + 255) / 256)   /* 196 scan blocks */

static __device__ __forceinline__ float b2f(bf16 v){ return __bfloat162float(v); }
static __device__ __forceinline__ bf16  f2b(float v){ return __float2bfloat16(v); }

__device__ __forceinline__ int clampi(int v, int hi){ return v < 0 ? 0 : (v >= hi ? hi - 1 : v); }

__device__ __forceinline__ float bf2f_bits(short s){
  return __uint_as_float(((unsigned)(unsigned short)s) << 16);
}
__device__ __forceinline__ short f2bf_bits(float v){      // RNE
  unsigned u = __float_as_uint(v);
  return (short)((u + 0x7fffu + ((u >> 16) & 1u)) >> 16);
}

// ---------------------------------------------------------------- fills
__global__ __launch_bounds__(256) void fill_u32(unsigned* __restrict__ p, unsigned v, int n){
  int i = blockIdx.x * 256 + threadIdx.x;
  if (i < n) p[i] = v;
}

// ---------------------------------------------------------------- dtype prep
__global__ __launch_bounds__(256) void conv_x(const float* __restrict__ x, bf16* __restrict__ XB){
  int i = blockIdx.x * 256 + threadIdx.x;
  if (i >= N_NODES * K1P) return;
  int n = i / K1P, k = i - n * K1P;
  XB[i] = f2b(k < IN_DIM ? x[(size_t)n * IN_DIM + k] : 0.f);
}

// 2 weight matrices -> contiguous transposed bf16 (layer-1 pair, K padded; small)
__global__ __launch_bounds__(256) void conv_wT2(const float* __restrict__ W0,
                                                const float* __restrict__ W1,
                                                bf16* __restrict__ WT,
                                                int K, int N, int Kp){
  int i = blockIdx.x * 256 + threadIdx.x;
  const int per = N * Kp;
  if (i >= 2 * per) return;
  int m = i / per, r = i - m * per;
  const float* W = m == 0 ? W0 : W1;
  int n = r / Kp, k = r - n * Kp;
  WT[i] = f2b(k < K ? W[(size_t)k * N + n] : 0.f);
}

// tiled transpose: 3x (640x640 f32, row-major k x n) -> bf16 WT[m][n][k]
__global__ __launch_bounds__(256) void conv_wT3t(const float* __restrict__ W0,
                                                 const float* __restrict__ W1,
                                                 const float* __restrict__ W2,
                                                 bf16* __restrict__ WT){
  __shared__ float t[32][33];
  int m = blockIdx.z;
  const float* W = m == 0 ? W0 : (m == 1 ? W1 : W2);
  int n0 = blockIdx.x * 32, k0 = blockIdx.y * 32;
  int tx = threadIdx.x & 31, ty = threadIdx.x >> 5;   // 32 x 8
#pragma unroll
  for (int r = 0; r < 32; r += 8)
    t[ty + r][tx] = W[(size_t)(k0 + ty + r) * HID + n0 + tx];   // coalesced in n
  __syncthreads();
  bf16* O = WT + (size_t)m * HID * HID;
#pragma unroll
  for (int r = 0; r < 32; r += 8)
    O[(size_t)(n0 + ty + r) * HID + k0 + tx] = f2b(t[tx][ty + r]);  // coalesced in k
}

// ---------------------------------------------------------------- MFMA GEMM (BK=64)
#define BM 128
#define BN 128
#define BK 64

typedef __attribute__((ext_vector_type(8))) short bf16x8;
typedef __attribute__((ext_vector_type(4))) float f32x4;

typedef const __attribute__((address_space(1))) unsigned gu32;
typedef __attribute__((address_space(3))) unsigned lu32;

__global__ __launch_bounds__(256) void mfma_gemm(const bf16* __restrict__ A,
                                                 const bf16* __restrict__ BT,
                                                 bf16* __restrict__ C0,
                                                 bf16* __restrict__ C1,
                                                 int M, int Kp, int NB){
  // block swizzle: all NB col-tiles of a row strip stay on one XCD (d%8 = XCD round-robin)
  int d   = blockIdx.x;
  int xcd = d & 7, j = d >> 3;
  int cb  = j % NB, ri = j / NB;
  int rb  = ri * 8 + xcd;
  const int row0 = rb * BM;
  if (row0 >= M) return;
  const int col0 = cb * BN;

  // LDS slot (r, kc) holds source k-chunk kc ^ (r&7): full 32-bank coverage, 2-way (free)
  __shared__ short As[BM * BK];   // 16 KB
  __shared__ short Bs[BN * BK];   // 16 KB
  const int tid  = threadIdx.x;
  const int lane = tid & 63;
  const int wave = tid >> 6;
  const int wr   = (wave >> 1) * 64;
  const int wc   = (wave & 1) * 64;
  const int l15  = lane & 15;
  const int quad = lane >> 4;
  const int sw   = l15 & 7;       // row-XOR term (wr, i*16 are multiples of 8)

  const bf16* aptr[4];
  const bf16* bptr[4];
  lu32* lda[4];
  lu32* ldb[4];
#pragma unroll
  for (int t = 0; t < 4; ++t){
    int ci = (t * 4 + wave) * 64 + lane;
    int r  = ci >> 3;
    int sc = (ci & 7) ^ (r & 7);
    int gr = row0 + r; if (gr >= M) gr = M - 1;
    aptr[t] = A  + (size_t)gr * Kp + sc * 8;
    bptr[t] = BT + (size_t)(col0 + r) * Kp + sc * 8;
    lda[t]  = (lu32*)(&As[(t * 4 + wave) * 512]);
    ldb[t]  = (lu32*)(&Bs[(t * 4 + wave) * 512]);
  }

  f32x4 acc[4][4];
#pragma unroll
  for (int i = 0; i < 4; ++i)
#pragma unroll
    for (int jj = 0; jj < 4; ++jj) acc[i][jj] = (f32x4){0.f, 0.f, 0.f, 0.f};

  for (int k0 = 0; k0 < Kp; k0 += BK){
#pragma unroll
    for (int t = 0; t < 4; ++t){
      __builtin_amdgcn_global_load_lds((gu32*)(aptr[t] + k0), lda[t], 16, 0, 0);
      __builtin_amdgcn_global_load_lds((gu32*)(bptr[t] + k0), ldb[t], 16, 0, 0);
    }
    __syncthreads();

#pragma unroll
    for (int ks = 0; ks < 2; ++ks){
      const int slotA = ((ks * 4 + quad) ^ sw) * 8;
      bf16x8 af[4], bfr[4];
#pragma unroll
      for (int i = 0; i < 4; ++i)
        af[i] = *(bf16x8*)(&As[(wr + i * 16 + l15) * BK + slotA]);
#pragma unroll
      for (int jj = 0; jj < 4; ++jj)
        bfr[jj] = *(bf16x8*)(&Bs[(wc + jj * 16 + l15) * BK + slotA]);
#pragma unroll
      for (int i = 0; i < 4; ++i)
#pragma unroll
        for (int jj = 0; jj < 4; ++jj)
          acc[i][jj] = __builtin_amdgcn_mfma_f32_16x16x32_bf16(af[i], bfr[jj], acc[i][jj], 0, 0, 0);
    }
    __syncthreads();
  }

  // epilogue: C/D layout col=lane&15, row=quad*4+reg; column-split dual output
  if (row0 + BM <= M){          // full strip: no row guards
#pragma unroll
    for (int i = 0; i < 4; ++i){
#pragma unroll
      for (int jj = 0; jj < 4; ++jj){
        int gc = col0 + wc + jj * 16 + l15;
        bf16* Cp = (gc < HID) ? C0 : C1;
        size_t cc = (gc < HID) ? gc : gc - HID;
        size_t base = (size_t)(row0 + wr + i * 16 + quad * 4) * HID + cc;
#pragma unroll
        for (int r = 0; r < 4; ++r)
          Cp[base + (size_t)r * HID] = f2b(acc[i][jj][r]);
      }
    }
  } else {
#pragma unroll
    for (int i = 0; i < 4; ++i){
#pragma unroll
      for (int jj = 0; jj < 4; ++jj){
        int gc = col0 + wc + jj * 16 + l15;
        bf16* Cp = (gc < HID) ? C0 : C1;
        int cc   = (gc < HID) ? gc : gc - HID;
#pragma unroll
        for (int r = 0; r < 4; ++r){
          int gr = row0 + wr + i * 16 + quad * 4 + r;
          if (gr < M) Cp[(size_t)gr * HID + cc] = f2b(acc[i][jj][r]);
        }
      }
    }
  }
}

// ---------------------------------------------------------------- CSR build
__global__ __launch_bounds__(256) void count_deg(const int* __restrict__ edst, int* __restrict__ degi){
  int e = blockIdx.x * 256 + threadIdx.x;
  if (e >= N_EDGES) return;
  atomicAdd(&degi[clampi(edst[e], N_NODES)], 1);
}

// phase 1: per-block exclusive scan; block sums to bsum; dinv computed here
__global__ __launch_bounds__(256) void scan_blk(const int* __restrict__ degi,
                                                int* __restrict__ rowp,
                                                float* __restrict__ dinv,
                                                int* __restrict__ bsum){
  __shared__ int wsum[4];
  int b = blockIdx.x, tid = threadIdx.x;
  int i = b * 256 + tid;
  int lane = tid & 63, wv = tid >> 6;
  int v = (i < N_NODES) ? degi[i] : 0;
  int incl = v;
#pragma unroll
  for (int ofs = 1; ofs < 64; ofs <<= 1){
    int t = __shfl_up(incl, ofs);
    if (lane >= ofs) incl += t;
  }
  if (lane == 63) wsum[wv] = incl;
  __syncthreads();
  int woff = 0;
#pragma unroll
  for (int w = 0; w < 4; ++w) if (w < wv) woff += wsum[w];
  if (i < N_NODES){
    rowp[i] = woff + incl - v;            // block-local exclusive
    dinv[i] = rsqrtf((float)(v + 1));
  }
  if (tid == 0) bsum[b] = wsum[0] + wsum[1] + wsum[2] + wsum[3];
}

// phase 2: single block scans bsum[SCB] exclusive in place; total -> rowp[N_NODES]
__global__ __launch_bounds__(256) void scan_top(int* __restrict__ bsum, int* __restrict__ rowp){
  __shared__ int wsum[4];
  int tid = threadIdx.x, lane = tid & 63, wv = tid >> 6;
  int v = (tid < SCB) ? bsum[tid] : 0;
  int incl = v;
#pragma unroll
  for (int ofs = 1; ofs < 64; ofs <<= 1){
    int t = __shfl_up(incl, ofs);
    if (lane >= ofs) incl += t;
  }
  if (lane == 63) wsum[wv] = incl;
  __syncthreads();
  int woff = 0;
#pragma unroll
  for (int w = 0; w < 4; ++w) if (w < wv) woff += wsum[w];
  if (tid < SCB) bsum[tid] = woff + incl - v;
  if (tid == 255) rowp[N_NODES] = woff + incl;   // grand total (v=0 past SCB)
}

// phase 3: add block offsets; curs = rowp
__global__ __launch_bounds__(256) void scan_add(const int* __restrict__ bsum,
                                                int* __restrict__ rowp,
                                                int* __restrict__ curs){
  int i = blockIdx.x * 256 + threadIdx.x;
  if (i >= N_NODES) return;
  int r = rowp[i] + bsum[blockIdx.x];
  rowp[i] = r; curs[i] = r;
}

__global__ __launch_bounds__(256) void bucket_edges(const int* __restrict__ esrc,
                                                    const int* __restrict__ edst,
                                                    int* __restrict__ curs,
                                                    int* __restrict__ srcg,
                                                    int* __restrict__ dstg){
  int e = blockIdx.x * 256 + threadIdx.x;
  if (e >= N_EDGES) return;
  int d = clampi(edst[e], N_NODES);
  int pos = atomicAdd(&curs[d], 1);
  srcg[pos] = clampi(esrc[e], N_NODES);
  dstg[pos] = d;
}

// ---------------------------------------------------------------- GAT1 fused logits+aggregation
// lane l owns ch [8l,8l+8) (head l>>3) and ch {512+2l,513+2l} (head 8+(l>>5)).
// Logit per head: 3-step shfl_xor reduce within 8-lane group; 5-step for heads 8,9.
// Fixed-reference softmax: p = exp(l - l_self) (clamped at 60); self-loop = exp(0)=1.
// Edge loop: unified clamped 4-groups — ALWAYS 4 row-gathers in flight (invalid slots
// load a duplicate valid row, masked to 0 in the update) — no serial tail for deg<4.
__global__ __launch_bounds__(256) void gat1_fused(const bf16* __restrict__ xl,
                                                  const bf16* __restrict__ xr,
                                                  const int* __restrict__ srcg,
                                                  const int* __restrict__ rowp,
                                                  const float* __restrict__ att,
                                                  const float* __restrict__ bias,
                                                  bf16* __restrict__ H){
  int n    = (blockIdx.x * 256 + threadIdx.x) >> 6;
  int lane = threadIdx.x & 63;
  if (n >= N_NODES) return;
  int r0 = rowp[n], r1 = rowp[n + 1];

  // attention weights for this lane's channels (att is [10][64] row-major => ch-major)
  float4 aA0 = *(const float4*)(att + 8 * lane);
  float4 aA1 = *(const float4*)(att + 8 * lane + 4);
  float2 aBv = *(const float2*)(att + 512 + 2 * lane);
  float attA[8] = {aA0.x, aA0.y, aA0.z, aA0.w, aA1.x, aA1.y, aA1.z, aA1.w};
  float attB0 = aBv.x, attB1 = aBv.y;

  // xr[n] (target transform) for this lane's channels
  const bf16* xrn = xr + (size_t)n * HID;
  bf16x8 vr = *(const bf16x8*)(xrn + 8 * lane);
  unsigned ur = *(const unsigned*)(xrn + 512 + 2 * lane);
  float xrA[8];
#pragma unroll
  for (int j = 0; j < 8; ++j) xrA[j] = bf2f_bits(vr[j]);
  float xrB0 = bf2f_bits((short)(ur & 0xffff));
  float xrB1 = bf2f_bits((short)(ur >> 16));

  // logit from a gathered source row (per-lane channels) -> per-lane head logits
  auto logits = [&](const float* xA, float xB0, float xB1, float& lA, float& lB){
    float pa = 0.f;
#pragma unroll
    for (int j = 0; j < 8; ++j){
      float s = xA[j] + xrA[j];
      s *= (s > 0.f) ? 1.f : NEG_SLOPE;
      pa = fmaf(attA[j], s, pa);
    }
    pa += __shfl_xor(pa, 1);
    pa += __shfl_xor(pa, 2);
    pa += __shfl_xor(pa, 4);
    lA = pa;
    float s0 = xB0 + xrB0; s0 *= (s0 > 0.f) ? 1.f : NEG_SLOPE;
    float s1 = xB1 + xrB1; s1 *= (s1 > 0.f) ? 1.f : NEG_SLOPE;
    float pb = attB0 * s0 + attB1 * s1;
    pb += __shfl_xor(pb, 1);
    pb += __shfl_xor(pb, 2);
    pb += __shfl_xor(pb, 4);
    pb += __shfl_xor(pb, 8);
    pb += __shfl_xor(pb, 16);
    lB = pb;
  };

  float accA[8], accB0, accB1, lsA, lsB;
  float denA = 1.f, denB = 1.f;

  // self-loop: reference logit, weight exp(0)=1
  {
    const bf16* xn = xl + (size_t)n * HID;
    bf16x8 v0 = *(const bf16x8*)(xn + 8 * lane);
    unsigned u0 = *(const unsigned*)(xn + 512 + 2 * lane);
    float sA[8];
#pragma unroll
    for (int j = 0; j < 8; ++j){ sA[j] = bf2f_bits(v0[j]); accA[j] = sA[j]; }
    float sB0 = bf2f_bits((short)(u0 & 0xffff));
    float sB1 = bf2f_bits((short)(u0 >> 16));
    accB0 = sB0; accB1 = sB1;
    logits(sA, sB0, sB1, lsA, lsB);
  }

  // masked per-edge accumulation (independent; msk=0 kills duplicate slots)
  auto upd1 = [&](const float* yA, float yB0, float yB1, float msk){
    float lA, lB;
    logits(yA, yB0, yB1, lA, lB);
    float pA = __expf(fminf(lA - lsA, 60.f)) * msk;
    float pB = __expf(fminf(lB - lsB, 60.f)) * msk;
    denA += pA; denB += pB;
#pragma unroll
    for (int j = 0; j < 8; ++j) accA[j] = fmaf(pA, yA[j], accA[j]);
    accB0 = fmaf(pB, yB0, accB0);
    accB1 = fmaf(pB, yB1, accB1);
  };

  for (int p = r0; p < r1; p += 4){
    int m = r1 - p;                      // 1..4 valid slots
    int i0 = srcg[p];
    int i1 = srcg[(m > 1) ? p + 1 : p];
    int i2 = srcg[(m > 2) ? p + 2 : p];
    int i3 = srcg[(m > 3) ? p + 3 : p];
    const bf16* q0 = xl + (size_t)i0 * HID;
    const bf16* q1 = xl + (size_t)i1 * HID;
    const bf16* q2 = xl + (size_t)i2 * HID;
    const bf16* q3 = xl + (size_t)i3 * HID;
    // issue all 8 row loads before any compute (hide gather latency)
    bf16x8 w0 = *(const bf16x8*)(q0 + 8 * lane);
    bf16x8 w1 = *(const bf16x8*)(q1 + 8 * lane);
    bf16x8 w2 = *(const bf16x8*)(q2 + 8 * lane);
    bf16x8 w3 = *(const bf16x8*)(q3 + 8 * lane);
    unsigned t0 = *(const unsigned*)(q0 + 512 + 2 * lane);
    unsigned t1 = *(const unsigned*)(q1 + 512 + 2 * lane);
    unsigned t2 = *(const unsigned*)(q2 + 512 + 2 * lane);
    unsigned t3 = *(const unsigned*)(q3 + 512 + 2 * lane);
    float k1 = (m > 1) ? 1.f : 0.f;
    float k2 = (m > 2) ? 1.f : 0.f;
    float k3 = (m > 3) ? 1.f : 0.f;
    {
      float yA0[8];
#pragma unroll
      for (int j = 0; j < 8; ++j) yA0[j] = bf2f_bits(w0[j]);
      upd1(yA0, bf2f_bits((short)(t0 & 0xffff)), bf2f_bits((short)(t0 >> 16)), 1.f);
    }
    {
      float yA1[8];
#pragma unroll
      for (int j = 0; j < 8; ++j) yA1[j] = bf2f_bits(w1[j]);
      upd1(yA1, bf2f_bits((short)(t1 & 0xffff)), bf2f_bits((short)(t1 >> 16)), k1);
    }
    {
      float yA2[8];
#pragma unroll
      for (int j = 0; j < 8; ++j) yA2[j] = bf2f_bits(w2[j]);
      upd1(yA2, bf2f_bits((short)(t2 & 0xffff)), bf2f_bits((short)(t2 >> 16)), k2);
    }
    {
      float yA3[8];
#pragma unroll
      for (int j = 0; j < 8; ++j) yA3[j] = bf2f_bits(w3[j]);
      upd1(yA3, bf2f_bits((short)(t3 & 0xffff)), bf2f_bits((short)(t3 >> 16)), k3);
    }
  }

  float invA = 1.f / denA, invB = 1.f / denB;
  float4 bA0 = *(const float4*)(bias + 8 * lane);
  float4 bA1 = *(const float4*)(bias + 8 * lane + 4);
  float2 bB  = *(const float2*)(bias + 512 + 2 * lane);
  float bAa[8] = {bA0.x, bA0.y, bA0.z, bA0.w, bA1.x, bA1.y, bA1.z, bA1.w};
  bf16x8 oA;
#pragma unroll
  for (int j = 0; j < 8; ++j){
    float v = accA[j] * invA + bAa[j];
    v = v > 0.f ? v : (__expf(v) - 1.f);              // ELU
    oA[j] = f2bf_bits(v);
  }
  float vb0 = accB0 * invB + bB.x; vb0 = vb0 > 0.f ? vb0 : (__expf(vb0) - 1.f);
  float vb1 = accB1 * invB + bB.y; vb1 = vb1 > 0.f ? vb1 : (__expf(vb1) - 1.f);
  bf16* hn = H + (size_t)n * HID;
  *(bf16x8*)(hn + 8 * lane) = oA;
  unsigned ob = (unsigned)(unsigned short)f2bf_bits(vb0) |
                ((unsigned)(unsigned short)f2bf_bits(vb1) << 16);
  *(unsigned*)(hn + 512 + 2 * lane) = ob;
}

// ---------------------------------------------------------------- GAT2 fused (1 head, full-wave logit reduce)
// Fixed-reference softmax + clamped 4-group edge loop (see gat1).
__global__ __launch_bounds__(256) void gat2_fused(const bf16* __restrict__ xl,
                                                  const bf16* __restrict__ xr,
                                                  const int* __restrict__ srcg,
                                                  const int* __restrict__ rowp,
                                                  const float* __restrict__ att,
                                                  const float* __restrict__ bias,
                                                  bf16* __restrict__ H){
  int n    = (blockIdx.x * 256 + threadIdx.x) >> 6;
  int lane = threadIdx.x & 63;
  if (n >= N_NODES) return;
  int r0 = rowp[n], r1 = rowp[n + 1];

  float4 aA0 = *(const float4*)(att + 8 * lane);
  float4 aA1 = *(const float4*)(att + 8 * lane + 4);
  float2 aBv = *(const float2*)(att + 512 + 2 * lane);
  float attA[8] = {aA0.x, aA0.y, aA0.z, aA0.w, aA1.x, aA1.y, aA1.z, aA1.w};
  float attB0 = aBv.x, attB1 = aBv.y;

  const bf16* xrn = xr + (size_t)n * HID;
  bf16x8 vr = *(const bf16x8*)(xrn + 8 * lane);
  unsigned ur = *(const unsigned*)(xrn + 512 + 2 * lane);
  float xrA[8];
#pragma unroll
  for (int j = 0; j < 8; ++j) xrA[j] = bf2f_bits(vr[j]);
  float xrB0 = bf2f_bits((short)(ur & 0xffff));
  float xrB1 = bf2f_bits((short)(ur >> 16));

  auto logit1 = [&](const float* xA, float xB0, float xB1)->float{
    float s0 = xB0 + xrB0; s0 *= (s0 > 0.f) ? 1.f : NEG_SLOPE;
    float s1 = xB1 + xrB1; s1 *= (s1 > 0.f) ? 1.f : NEG_SLOPE;
    float pa = attB0 * s0 + attB1 * s1;
#pragma unroll
    for (int j = 0; j < 8; ++j){
      float s = xA[j] + xrA[j];
      s *= (s > 0.f) ? 1.f : NEG_SLOPE;
      pa = fmaf(attA[j], s, pa);
    }
    pa += __shfl_xor(pa, 1);
    pa += __shfl_xor(pa, 2);
    pa += __shfl_xor(pa, 4);
    pa += __shfl_xor(pa, 8);
    pa += __shfl_xor(pa, 16);
    pa += __shfl_xor(pa, 32);
    return pa;
  };

  float accA[8], accB0, accB1, ls;
  float den = 1.f;
  {
    const bf16* xn = xl + (size_t)n * HID;
    bf16x8 v0 = *(const bf16x8*)(xn + 8 * lane);
    unsigned u0 = *(const unsigned*)(xn + 512 + 2 * lane);
    float sA[8];
#pragma unroll
    for (int j = 0; j < 8; ++j){ sA[j] = bf2f_bits(v0[j]); accA[j] = sA[j]; }
    float sB0 = bf2f_bits((short)(u0 & 0xffff));
    float sB1 = bf2f_bits((short)(u0 >> 16));
    accB0 = sB0; accB1 = sB1;
    ls = logit1(sA, sB0, sB1);
  }

  auto upd1 = [&](const float* yA, float yB0, float yB1, float msk){
    float l = logit1(yA, yB0, yB1);
    float pv = __expf(fminf(l - ls, 60.f)) * msk;
    den += pv;
#pragma unroll
    for (int j = 0; j < 8; ++j) accA[j] = fmaf(pv, yA[j], accA[j]);
    accB0 = fmaf(pv, yB0, accB0);
    accB1 = fmaf(pv, yB1, accB1);
  };

  for (int p = r0; p < r1; p += 4){
    int m = r1 - p;
    int i0 = srcg[p];
    int i1 = srcg[(m > 1) ? p + 1 : p];
    int i2 = srcg[(m > 2) ? p + 2 : p];
    int i3 = srcg[(m > 3) ? p + 3 : p];
    const bf16* q0 = xl + (size_t)i0 * HID;
    const bf16* q1 = xl + (size_t)i1 * HID;
    const bf16* q2 = xl + (size_t)i2 * HID;
    const bf16* q3 = xl + (size_t)i3 * HID;
    bf16x8 w0 = *(const bf16x8*)(q0 + 8 * lane);
    bf16x8 w1 = *(const bf16x8*)(q1 + 8 * lane);
    bf16x8 w2 = *(const bf16x8*)(q2 + 8 * lane);
    bf16x8 w3 = *(const bf16x8*)(q3 + 8 * lane);
    unsigned t0 = *(const unsigned*)(q0 + 512 + 2 * lane);
    unsigned t1 = *(const unsigned*)(q1 + 512 + 2 * lane);
    unsigned t2 = *(const unsigned*)(q2 + 512 + 2 * lane);
    unsigned t3 = *(const unsigned*)(q3 + 512 + 2 * lane);
    float k1 = (m > 1) ? 1.f : 0.f;
    float k2 = (m > 2) ? 1.f : 0.f;
    float k3 = (m > 3) ? 1.f : 0.f;
    {
      float yA0[8];
#pragma unroll
      for (int j = 0; j < 8; ++j) yA0[j] = bf2f_bits(w0[j]);
      upd1(yA0, bf2f_bits((short)(t0 & 0xffff)), bf2f_bits((short)(t0 >> 16)), 1.f);
    }
    {
      float yA1[8];
#pragma unroll
      for (int j = 0; j < 8; ++j) yA1[j] = bf2f_bits(w1[j]);
      upd1(yA1, bf2f_bits((short)(t1 & 0xffff)), bf2f_bits((short)(t1 >> 16)), k1);
    }
    {
      float yA2[8];
#pragma unroll
      for (int j = 0; j < 8; ++j) yA2[j] = bf2f_bits(w2[j]);
      upd1(yA2, bf2f_bits((short)(t2 & 0xffff)), bf2f_bits((short)(t2 >> 16)), k2);
    }
    {
      float yA3[8];
#pragma unroll
      for (int j = 0; j < 8; ++j) yA3[j] = bf2f_bits(w3[j]);
      upd1(yA3, bf2f_bits((short)(t3 & 0xffff)), bf2f_bits((short)(t3 >> 16)), k3);
    }
  }

  float inv = 1.f / den;
  float4 bA0 = *(const float4*)(bias + 8 * lane);
  float4 bA1 = *(const float4*)(bias + 8 * lane + 4);
  float2 bB  = *(const float2*)(bias + 512 + 2 * lane);
  float bAa[8] = {bA0.x, bA0.y, bA0.z, bA0.w, bA1.x, bA1.y, bA1.z, bA1.w};
  bf16x8 oA;
#pragma unroll
  for (int j = 0; j < 8; ++j) oA[j] = f2bf_bits(accA[j] * inv + bAa[j]);
  bf16* hn = H + (size_t)n * HID;
  *(bf16x8*)(hn + 8 * lane) = oA;
  unsigned ob = (unsigned)(unsigned short)f2bf_bits(accB0 * inv + bB.x) |
                ((unsigned)(unsigned short)f2bf_bits(accB1 * inv + bB.y) << 16);
  *(unsigned*)(hn + 512 + 2 * lane) = ob;
}

// ---------------------------------------------------------------- fused GCN + pooling (block per graph)
// batch is sorted -> each graph is a contiguous node range [gstart[g], gstart[g+1]).
// 4 waves round-robin the graph's nodes; clamped 4-group edge loop (zero-weight dups);
// pool max/sum in registers; one LDS reduction writes 2x640 f32 output. No h3 roundtrip.
__global__ __launch_bounds__(256) void gcn_pool(const bf16* __restrict__ xw,
                                                const int* __restrict__ srcg,
                                                const int* __restrict__ rowp,
                                                const float* __restrict__ dinv,
                                                const float* __restrict__ bg,
                                                const int* __restrict__ gstart,
                                                float* __restrict__ out){
  __shared__ float red[8][HID];      // [0..3]=max partials, [4..7]=sum partials (20.5 KB)
  int g    = blockIdx.x;
  int n0   = gstart[g], n1 = gstart[g + 1];
  int lane = threadIdx.x & 63;
  int wv   = threadIdx.x >> 6;

  float4 bA0 = *(const float4*)(bg + 8 * lane);
  float4 bA1 = *(const float4*)(bg + 8 * lane + 4);
  float2 bB  = *(const float2*)(bg + 512 + 2 * lane);
  float bAa[8] = {bA0.x, bA0.y, bA0.z, bA0.w, bA1.x, bA1.y, bA1.z, bA1.w};

  float mxA[8] = {0.f,0.f,0.f,0.f,0.f,0.f,0.f,0.f};
  float smA[8] = {0.f,0.f,0.f,0.f,0.f,0.f,0.f,0.f};
  float mxB0 = 0.f, mxB1 = 0.f, smB0 = 0.f, smB1 = 0.f;

  for (int n = n0 + wv; n < n1; n += 4){
    int r0 = rowp[n], r1 = rowp[n + 1];
    float dn = dinv[n];
    float accA[8], accB[2];
    {
      float w = dn * dn;
      const bf16* xn = xw + (size_t)n * HID;
      bf16x8 va = *(const bf16x8*)(xn + 8 * lane);
      unsigned vb = *(const unsigned*)(xn + 512 + 2 * lane);
#pragma unroll
      for (int j = 0; j < 8; ++j) accA[j] = w * bf2f_bits(va[j]);
      accB[0] = w * bf2f_bits((short)(vb & 0xffff));
      accB[1] = w * bf2f_bits((short)(vb >> 16));
    }
    for (int p = r0; p < r1; p += 4){
      int m = r1 - p;
      int s0 = srcg[p];
      int s1 = srcg[(m > 1) ? p + 1 : p];
      int s2 = srcg[(m > 2) ? p + 2 : p];
      int s3 = srcg[(m > 3) ? p + 3 : p];
      const bf16* xs0 = xw + (size_t)s0 * HID;
      const bf16* xs1 = xw + (size_t)s1 * HID;
      const bf16* xs2 = xw + (size_t)s2 * HID;
      const bf16* xs3 = xw + (size_t)s3 * HID;
      float w0 = dinv[s0] * dn;
      float w1 = (m > 1) ? dinv[s1] * dn : 0.f;
      float w2 = (m > 2) ? dinv[s2] * dn : 0.f;
      float w3 = (m > 3) ? dinv[s3] * dn : 0.f;
      bf16x8 va0 = *(const bf16x8*)(xs0 + 8 * lane);
      bf16x8 va1 = *(const bf16x8*)(xs1 + 8 * lane);
      bf16x8 va2 = *(const bf16x8*)(xs2 + 8 * lane);
      bf16x8 va3 = *(const bf16x8*)(xs3 + 8 * lane);
      unsigned vb0 = *(const unsigned*)(xs0 + 512 + 2 * lane);
      unsigned vb1 = *(const unsigned*)(xs1 + 512 + 2 * lane);
      unsigned vb2 = *(const unsigned*)(xs2 + 512 + 2 * lane);
      unsigned vb3 = *(const unsigned*)(xs3 + 512 + 2 * lane);
#pragma unroll
      for (int j = 0; j < 8; ++j)
        accA[j] += w0 * bf2f_bits(va0[j]) + w1 * bf2f_bits(va1[j])
                 + w2 * bf2f_bits(va2[j]) + w3 * bf2f_bits(va3[j]);
      accB[0] += w0 * bf2f_bits((short)(vb0 & 0xffff)) + w1 * bf2f_bits((short)(vb1 & 0xffff))
               + w2 * bf2f_bits((short)(vb2 & 0xffff)) + w3 * bf2f_bits((short)(vb3 & 0xffff));
      accB[1] += w0 * bf2f_bits((short)(vb0 >> 16))    + w1 * bf2f_bits((short)(vb1 >> 16))
               + w2 * bf2f_bits((short)(vb2 >> 16))    + w3 * bf2f_bits((short)(vb3 >> 16));
    }
    // bias + ReLU (f32), then pool-accumulate
#pragma unroll
    for (int j = 0; j < 8; ++j){
      float v = fmaxf(accA[j] + bAa[j], 0.f);
      mxA[j] = fmaxf(mxA[j], v); smA[j] += v;
    }
    {
      float v0 = fmaxf(accB[0] + bB.x, 0.f);
      float v1 = fmaxf(accB[1] + bB.y, 0.f);
      mxB0 = fmaxf(mxB0, v0); smB0 += v0;
      mxB1 = fmaxf(mxB1, v1); smB1 += v1;
    }
  }

  // per-wave partials -> LDS
#pragma unroll
  for (int j = 0; j < 8; ++j){
    red[wv][8 * lane + j]     = mxA[j];
    red[4 + wv][8 * lane + j] = smA[j];
  }
  red[wv][512 + 2 * lane]         = mxB0;
  red[wv][512 + 2 * lane + 1]     = mxB1;
  red[4 + wv][512 + 2 * lane]     = smB0;
  red[4 + wv][512 + 2 * lane + 1] = smB1;
  __syncthreads();

  float inv = (n1 > n0) ? 1.f / (float)(n1 - n0) : 0.f;
  float* og = out + (size_t)g * 2 * HID;
  for (int c = threadIdx.x; c < HID; c += 256){
    float mx = fmaxf(fmaxf(red[0][c], red[1][c]), fmaxf(red[2][c], red[3][c]));
    float sm = red[4][c] + red[5][c] + red[6][c] + red[7][c];
    og[c]       = mx;
    og[HID + c] = sm * inv;
  }
}

// ---------------------------------------------------------------- per-graph bounds (batch is sorted)
__global__ __launch_bounds__(256) void graph_bounds(const int* __restrict__ batch,
                                                    int* __restrict__ gstart){
  int n = blockIdx.x * 256 + threadIdx.x;
  if (n >= N_NODES) return;
  int b = clampi(batch[n], N_GRAPHS);
  if (n == 0){
    for (int g = 0; g <= b; ++g) gstart[g] = 0;
  } else {
    int bp = clampi(batch[n - 1], N_GRAPHS);
    for (int g = bp + 1; g <= b; ++g) gstart[g] = n;
  }
  if (n == N_NODES - 1){
    for (int g = b + 1; g <= N_GRAPHS; ++g) gstart[g] = N_NODES;
  }
}

// ---------------------------------------------------------------- launch
extern "C" void kernel_launch(void* const* d_in, const int* in_sizes, int n_in,
                              void* d_out, int out_size, void* d_ws, size_t ws_size,
                              hipStream_t stream){
  const float* x     = (const float*)d_in[0];
  const int*   ei    = (const int*)d_in[1];
  const int*   batch = (const int*)d_in[2];
  const float* Wl1 = (const float*)d_in[3];
  const float* Wr1 = (const float*)d_in[4];
  const float* a1  = (const float*)d_in[5];
  const float* b1  = (const float*)d_in[6];
  const float* Wl2 = (const float*)d_in[7];
  const float* Wr2 = (const float*)d_in[8];
  const float* a2  = (const float*)d_in[9];
  const float* b2  = (const float*)d_in[10];
  const float* Wg  = (const float*)d_in[11];
  const float* bg  = (const float*)d_in[12];
  const int* esrc = ei;
  const int* edst = ei + N_EDGES;

  // ---- workspace layout ----
  char* ws = (char*)d_ws;
  size_t off = 0;
  auto take = [&](size_t bytes)->char*{
    char* p = ws + off; off = (off + bytes + 255) & ~(size_t)255; return p;
  };
  bf16*     X1   = (bf16*)    take((size_t)N_NODES * HID * 2);
  bf16*     X2   = (bf16*)    take((size_t)N_NODES * HID * 2);
  bf16*     H    = (bf16*)    take((size_t)N_NODES * HID * 2);
  bf16*     XB   = (bf16*)    take((size_t)N_NODES * K1P * 2);
  // WT1l|WT1r contiguous (one 1280xK1P matrix); WT2l|WT2r|WTg contiguous.
  bf16*     WT1l = (bf16*)    take((size_t)HID * K1P * 2);
  bf16*     WT1r = (bf16*)    take((size_t)HID * K1P * 2);
  bf16*     WT2l = (bf16*)    take((size_t)HID * HID * 2);
  bf16*     WT2r = (bf16*)    take((size_t)HID * HID * 2);
  bf16*     WTg  = (bf16*)    take((size_t)HID * HID * 2);
  int*      DEGI = (int*)     take((size_t)N_NODES * 4);
  int*      ROWP = (int*)     take((size_t)(N_NODES + 1) * 4);
  int*      CURS = (int*)     take((size_t)N_NODES * 4);
  int*      SRCG = (int*)     take((size_t)N_EDGES * 4);
  int*      DSTG = (int*)     take((size_t)N_EDGES * 4);
  float*    DINV = (float*)   take((size_t)N_NODES * 4);
  int*      GST  = (int*)     take((size_t)(N_GRAPHS + 1) * 4);
  int*      BSUM = (int*)     take((size_t)SCB * 4);
  (void)WT1r; (void)WT2r; (void)DSTG; (void)X2;

  dim3 blk(256);
  auto fill = [&](void* p, unsigned v, int n){
    fill_u32<<<dim3((n + 255) / 256), blk, 0, stream>>>((unsigned*)p, v, n);
  };
  const int MB8     = ((N_NODES + BM - 1) / BM + 7) / 8;   // 128-row strips per XCD (49)
  const int nblocks = (N_NODES * 64 + 255) / 256;
  const int reblk   = (N_EDGES + 255) / 256;

  // ---- prep + CSR ----
  conv_x<<<(N_NODES * K1P + 255) / 256, blk, 0, stream>>>(x, XB);
  conv_wT2<<<(2 * HID * K1P + 255) / 256, blk, 0, stream>>>(Wl1, Wr1, WT1l, IN_DIM, HID, K1P);
  conv_wT3t<<<dim3(HID / 32, HID / 32, 3), blk, 0, stream>>>(Wl2, Wr2, Wg, WT2l);
  fill(DEGI, 0u, N_NODES);
  count_deg<<<reblk, blk, 0, stream>>>(edst, DEGI);
  scan_blk<<<dim3(SCB), blk, 0, stream>>>(DEGI, ROWP, DINV, BSUM);
  scan_top<<<dim3(1), blk, 0, stream>>>(BSUM, ROWP);
  scan_add<<<dim3(SCB), blk, 0, stream>>>(BSUM, ROWP, CURS);
  bucket_edges<<<reblk, blk, 0, stream>>>(esrc, edst, CURS, SRCG, DSTG);
  graph_bounds<<<(N_NODES + 255) / 256, blk, 0, stream>>>(batch, GST);

  // ---- GATv2 layer 1 (merged Wl|Wr GEMM, N=1280; fused logits+agg) ----
  mfma_gemm<<<dim3(8 * MB8 * 10), blk, 0, stream>>>(XB, WT1l, X1, X2, N_NODES, K1P, 10);
  gat1_fused<<<nblocks, blk, 0, stream>>>(X1, X2, SRCG, ROWP, a1, b1, H);

  // ---- GATv2 layer 2 (merged Wl|Wr GEMM, N=1280; fused logits+agg) ----
  mfma_gemm<<<dim3(8 * MB8 * 10), blk, 0, stream>>>(H, WT2l, X1, X2, N_NODES, HID, 10);
  gat2_fused<<<nblocks, blk, 0, stream>>>(X1, X2, SRCG, ROWP, a2, b2, H);

  // ---- GCN GEMM + fused gather/pool (no h3 roundtrip) ----
  mfma_gemm<<<dim3(8 * MB8 * 5), blk, 0, stream>>>(H, WTg, X1, X1, N_NODES, HID, 5);
  gcn_pool<<<dim3(N_GRAPHS), blk, 0, stream>>>(X1, SRCG, ROWP, DINV, bg, GST, (float*)d_out);
}

// Round 9
// 497.990 us; speedup vs baseline: 1.0713x; 1.0713x over previous
//
#include <hip/hip_runtime.h>
#include <hip/hip_bf16.h>
#include <cstdint>
#include <cstddef>

typedef __hip_bfloat16 bf16;

#define N_NODES  50000
#define N_EDGES  150000
#define N_GRAPHS 1024
#define IN_DIM   78
#define K1P      128                   /* IN_DIM padded to mult of 64 (BK) */
#define OUT_DIM  64
#define HEADS    10
#define HID      640
#define NEG_SLOPE 0.2f
#define SCB      ((N_NODES + 255) / 256)   /* 196 scan blocks */

static __device__ __forceinline__ float b2f(bf16 v){ return __bfloat162float(v); }
static __device__ __forceinline__ bf16  f2b(float v){ return __float2bfloat16(v); }

__device__ __forceinline__ int clampi(int v, int hi){ return v < 0 ? 0 : (v >= hi ? hi - 1 : v); }

__device__ __forceinline__ float bf2f_bits(short s){
  return __uint_as_float(((unsigned)(unsigned short)s) << 16);
}
__device__ __forceinline__ short f2bf_bits(float v){      // RNE
  unsigned u = __float_as_uint(v);
  return (short)((u + 0x7fffu + ((u >> 16) & 1u)) >> 16);
}

// ---------------------------------------------------------------- fills
__global__ __launch_bounds__(256) void fill_u32(unsigned* __restrict__ p, unsigned v, int n){
  int i = blockIdx.x * 256 + threadIdx.x;
  if (i < n) p[i] = v;
}

// ---------------------------------------------------------------- dtype prep
__global__ __launch_bounds__(256) void conv_x(const float* __restrict__ x, bf16* __restrict__ XB){
  int i = blockIdx.x * 256 + threadIdx.x;
  if (i >= N_NODES * K1P) return;
  int n = i / K1P, k = i - n * K1P;
  XB[i] = f2b(k < IN_DIM ? x[(size_t)n * IN_DIM + k] : 0.f);
}

// 2 weight matrices -> contiguous transposed bf16 (layer-1 pair, K padded; small)
__global__ __launch_bounds__(256) void conv_wT2(const float* __restrict__ W0,
                                                const float* __restrict__ W1,
                                                bf16* __restrict__ WT,
                                                int K, int N, int Kp){
  int i = blockIdx.x * 256 + threadIdx.x;
  const int per = N * Kp;
  if (i >= 2 * per) return;
  int m = i / per, r = i - m * per;
  const float* W = m == 0 ? W0 : W1;
  int n = r / Kp, k = r - n * Kp;
  WT[i] = f2b(k < K ? W[(size_t)k * N + n] : 0.f);
}

// tiled transpose: 3x (640x640 f32, row-major k x n) -> bf16 WT[m][n][k]
__global__ __launch_bounds__(256) void conv_wT3t(const float* __restrict__ W0,
                                                 const float* __restrict__ W1,
                                                 const float* __restrict__ W2,
                                                 bf16* __restrict__ WT){
  __shared__ float t[32][33];
  int m = blockIdx.z;
  const float* W = m == 0 ? W0 : (m == 1 ? W1 : W2);
  int n0 = blockIdx.x * 32, k0 = blockIdx.y * 32;
  int tx = threadIdx.x & 31, ty = threadIdx.x >> 5;   // 32 x 8
#pragma unroll
  for (int r = 0; r < 32; r += 8)
    t[ty + r][tx] = W[(size_t)(k0 + ty + r) * HID + n0 + tx];   // coalesced in n
  __syncthreads();
  bf16* O = WT + (size_t)m * HID * HID;
#pragma unroll
  for (int r = 0; r < 32; r += 8)
    O[(size_t)(n0 + ty + r) * HID + k0 + tx] = f2b(t[tx][ty + r]);  // coalesced in k
}

// ---------------------------------------------------------------- MFMA GEMM (BK=64)
#define BM 128
#define BN 128
#define BK 64

typedef __attribute__((ext_vector_type(8))) short bf16x8;
typedef __attribute__((ext_vector_type(4))) float f32x4;

typedef const __attribute__((address_space(1))) unsigned gu32;
typedef __attribute__((address_space(3))) unsigned lu32;

__global__ __launch_bounds__(256) void mfma_gemm(const bf16* __restrict__ A,
                                                 const bf16* __restrict__ BT,
                                                 bf16* __restrict__ C0,
                                                 bf16* __restrict__ C1,
                                                 int M, int Kp, int NB){
  // block swizzle: all NB col-tiles of a row strip stay on one XCD (d%8 = XCD round-robin)
  int d   = blockIdx.x;
  int xcd = d & 7, j = d >> 3;
  int cb  = j % NB, ri = j / NB;
  int rb  = ri * 8 + xcd;
  const int row0 = rb * BM;
  if (row0 >= M) return;
  const int col0 = cb * BN;

  // LDS slot (r, kc) holds source k-chunk kc ^ (r&7): full 32-bank coverage, 2-way (free)
  __shared__ short As[BM * BK];   // 16 KB
  __shared__ short Bs[BN * BK];   // 16 KB
  const int tid  = threadIdx.x;
  const int lane = tid & 63;
  const int wave = tid >> 6;
  const int wr   = (wave >> 1) * 64;
  const int wc   = (wave & 1) * 64;
  const int l15  = lane & 15;
  const int quad = lane >> 4;
  const int sw   = l15 & 7;       // row-XOR term (wr, i*16 are multiples of 8)

  const bf16* aptr[4];
  const bf16* bptr[4];
  lu32* lda[4];
  lu32* ldb[4];
#pragma unroll
  for (int t = 0; t < 4; ++t){
    int ci = (t * 4 + wave) * 64 + lane;
    int r  = ci >> 3;
    int sc = (ci & 7) ^ (r & 7);
    int gr = row0 + r; if (gr >= M) gr = M - 1;
    aptr[t] = A  + (size_t)gr * Kp + sc * 8;
    bptr[t] = BT + (size_t)(col0 + r) * Kp + sc * 8;
    lda[t]  = (lu32*)(&As[(t * 4 + wave) * 512]);
    ldb[t]  = (lu32*)(&Bs[(t * 4 + wave) * 512]);
  }

  f32x4 acc[4][4];
#pragma unroll
  for (int i = 0; i < 4; ++i)
#pragma unroll
    for (int jj = 0; jj < 4; ++jj) acc[i][jj] = (f32x4){0.f, 0.f, 0.f, 0.f};

  for (int k0 = 0; k0 < Kp; k0 += BK){
#pragma unroll
    for (int t = 0; t < 4; ++t){
      __builtin_amdgcn_global_load_lds((gu32*)(aptr[t] + k0), lda[t], 16, 0, 0);
      __builtin_amdgcn_global_load_lds((gu32*)(bptr[t] + k0), ldb[t], 16, 0, 0);
    }
    __syncthreads();

#pragma unroll
    for (int ks = 0; ks < 2; ++ks){
      const int slotA = ((ks * 4 + quad) ^ sw) * 8;
      bf16x8 af[4], bfr[4];
#pragma unroll
      for (int i = 0; i < 4; ++i)
        af[i] = *(bf16x8*)(&As[(wr + i * 16 + l15) * BK + slotA]);
#pragma unroll
      for (int jj = 0; jj < 4; ++jj)
        bfr[jj] = *(bf16x8*)(&Bs[(wc + jj * 16 + l15) * BK + slotA]);
#pragma unroll
      for (int i = 0; i < 4; ++i)
#pragma unroll
        for (int jj = 0; jj < 4; ++jj)
          acc[i][jj] = __builtin_amdgcn_mfma_f32_16x16x32_bf16(af[i], bfr[jj], acc[i][jj], 0, 0, 0);
    }
    __syncthreads();
  }

  // epilogue: C/D layout col=lane&15, row=quad*4+reg; column-split dual output
  if (row0 + BM <= M){          // full strip: no row guards
#pragma unroll
    for (int i = 0; i < 4; ++i){
#pragma unroll
      for (int jj = 0; jj < 4; ++jj){
        int gc = col0 + wc + jj * 16 + l15;
        bf16* Cp = (gc < HID) ? C0 : C1;
        size_t cc = (gc < HID) ? gc : gc - HID;
        size_t base = (size_t)(row0 + wr + i * 16 + quad * 4) * HID + cc;
#pragma unroll
        for (int r = 0; r < 4; ++r)
          Cp[base + (size_t)r * HID] = f2b(acc[i][jj][r]);
      }
    }
  } else {
#pragma unroll
    for (int i = 0; i < 4; ++i){
#pragma unroll
      for (int jj = 0; jj < 4; ++jj){
        int gc = col0 + wc + jj * 16 + l15;
        bf16* Cp = (gc < HID) ? C0 : C1;
        int cc   = (gc < HID) ? gc : gc - HID;
#pragma unroll
        for (int r = 0; r < 4; ++r){
          int gr = row0 + wr + i * 16 + quad * 4 + r;
          if (gr < M) Cp[(size_t)gr * HID + cc] = f2b(acc[i][jj][r]);
        }
      }
    }
  }
}

// ---------------------------------------------------------------- CSR build
__global__ __launch_bounds__(256) void count_deg(const int* __restrict__ edst, int* __restrict__ degi){
  int e = blockIdx.x * 256 + threadIdx.x;
  if (e >= N_EDGES) return;
  atomicAdd(&degi[clampi(edst[e], N_NODES)], 1);
}

// phase 1: per-block exclusive scan; block sums to bsum; dinv computed here
__global__ __launch_bounds__(256) void scan_blk(const int* __restrict__ degi,
                                                int* __restrict__ rowp,
                                                float* __restrict__ dinv,
                                                int* __restrict__ bsum){
  __shared__ int wsum[4];
  int b = blockIdx.x, tid = threadIdx.x;
  int i = b * 256 + tid;
  int lane = tid & 63, wv = tid >> 6;
  int v = (i < N_NODES) ? degi[i] : 0;
  int incl = v;
#pragma unroll
  for (int ofs = 1; ofs < 64; ofs <<= 1){
    int t = __shfl_up(incl, ofs);
    if (lane >= ofs) incl += t;
  }
  if (lane == 63) wsum[wv] = incl;
  __syncthreads();
  int woff = 0;
#pragma unroll
  for (int w = 0; w < 4; ++w) if (w < wv) woff += wsum[w];
  if (i < N_NODES){
    rowp[i] = woff + incl - v;            // block-local exclusive
    dinv[i] = rsqrtf((float)(v + 1));
  }
  if (tid == 0) bsum[b] = wsum[0] + wsum[1] + wsum[2] + wsum[3];
}

// phase 2: single block scans bsum[SCB] exclusive in place; total -> rowp[N_NODES]
__global__ __launch_bounds__(256) void scan_top(int* __restrict__ bsum, int* __restrict__ rowp){
  __shared__ int wsum[4];
  int tid = threadIdx.x, lane = tid & 63, wv = tid >> 6;
  int v = (tid < SCB) ? bsum[tid] : 0;
  int incl = v;
#pragma unroll
  for (int ofs = 1; ofs < 64; ofs <<= 1){
    int t = __shfl_up(incl, ofs);
    if (lane >= ofs) incl += t;
  }
  if (lane == 63) wsum[wv] = incl;
  __syncthreads();
  int woff = 0;
#pragma unroll
  for (int w = 0; w < 4; ++w) if (w < wv) woff += wsum[w];
  if (tid < SCB) bsum[tid] = woff + incl - v;
  if (tid == 255) rowp[N_NODES] = woff + incl;   // grand total (v=0 past SCB)
}

// phase 3: add block offsets; curs = rowp
__global__ __launch_bounds__(256) void scan_add(const int* __restrict__ bsum,
                                                int* __restrict__ rowp,
                                                int* __restrict__ curs){
  int i = blockIdx.x * 256 + threadIdx.x;
  if (i >= N_NODES) return;
  int r = rowp[i] + bsum[blockIdx.x];
  rowp[i] = r; curs[i] = r;
}

__global__ __launch_bounds__(256) void bucket_edges(const int* __restrict__ esrc,
                                                    const int* __restrict__ edst,
                                                    int* __restrict__ curs,
                                                    int* __restrict__ srcg,
                                                    int* __restrict__ dstg){
  int e = blockIdx.x * 256 + threadIdx.x;
  if (e >= N_EDGES) return;
  int d = clampi(edst[e], N_NODES);
  int pos = atomicAdd(&curs[d], 1);
  srcg[pos] = clampi(esrc[e], N_NODES);
  dstg[pos] = d;
}

// ---------------------------------------------------------------- GAT1 fused logits+aggregation
// lane l owns ch [8l,8l+8) (head l>>3) and ch {512+2l,513+2l} (head 8+(l>>5)).
// Logit per head: 3-step shfl_xor reduce within 8-lane group (heads 0-7);
// 5-step reduce within 32-lane half (heads 8,9).
// Fixed-reference softmax: p = exp(l - l_self) (clamped at 60); self-loop = exp(0)=1.
// alpha = p/Σp is reference-invariant; removes the online-max serial chain so the
// 4-edge issue groups are fully independent (T13-limit + T14). Real edges only
// (round-8 lesson: duplicate masked loads cost more than the latency they hide).
__global__ __launch_bounds__(256) void gat1_fused(const bf16* __restrict__ xl,
                                                  const bf16* __restrict__ xr,
                                                  const int* __restrict__ srcg,
                                                  const int* __restrict__ rowp,
                                                  const float* __restrict__ att,
                                                  const float* __restrict__ bias,
                                                  bf16* __restrict__ H){
  int n    = (blockIdx.x * 256 + threadIdx.x) >> 6;
  int lane = threadIdx.x & 63;
  if (n >= N_NODES) return;
  int r0 = rowp[n], r1 = rowp[n + 1];

  // attention weights for this lane's channels (att is [10][64] row-major => ch-major)
  float4 aA0 = *(const float4*)(att + 8 * lane);
  float4 aA1 = *(const float4*)(att + 8 * lane + 4);
  float2 aBv = *(const float2*)(att + 512 + 2 * lane);
  float attA[8] = {aA0.x, aA0.y, aA0.z, aA0.w, aA1.x, aA1.y, aA1.z, aA1.w};
  float attB0 = aBv.x, attB1 = aBv.y;

  // xr[n] (target transform) for this lane's channels
  const bf16* xrn = xr + (size_t)n * HID;
  bf16x8 vr = *(const bf16x8*)(xrn + 8 * lane);
  unsigned ur = *(const unsigned*)(xrn + 512 + 2 * lane);
  float xrA[8];
#pragma unroll
  for (int j = 0; j < 8; ++j) xrA[j] = bf2f_bits(vr[j]);
  float xrB0 = bf2f_bits((short)(ur & 0xffff));
  float xrB1 = bf2f_bits((short)(ur >> 16));

  // logit from a gathered source row (per-lane channels) -> per-lane head logits
  auto logits = [&](const float* xA, float xB0, float xB1, float& lA, float& lB){
    float pa = 0.f;
#pragma unroll
    for (int j = 0; j < 8; ++j){
      float s = xA[j] + xrA[j];
      s *= (s > 0.f) ? 1.f : NEG_SLOPE;
      pa = fmaf(attA[j], s, pa);
    }
    pa += __shfl_xor(pa, 1);
    pa += __shfl_xor(pa, 2);
    pa += __shfl_xor(pa, 4);
    lA = pa;
    float s0 = xB0 + xrB0; s0 *= (s0 > 0.f) ? 1.f : NEG_SLOPE;
    float s1 = xB1 + xrB1; s1 *= (s1 > 0.f) ? 1.f : NEG_SLOPE;
    float pb = attB0 * s0 + attB1 * s1;
    pb += __shfl_xor(pb, 1);
    pb += __shfl_xor(pb, 2);
    pb += __shfl_xor(pb, 4);
    pb += __shfl_xor(pb, 8);
    pb += __shfl_xor(pb, 16);
    lB = pb;
  };

  float accA[8], accB0, accB1, lsA, lsB;
  float denA = 1.f, denB = 1.f;

  // self-loop: reference logit, weight exp(0)=1
  {
    const bf16* xn = xl + (size_t)n * HID;
    bf16x8 v0 = *(const bf16x8*)(xn + 8 * lane);
    unsigned u0 = *(const unsigned*)(xn + 512 + 2 * lane);
    float sA[8];
#pragma unroll
    for (int j = 0; j < 8; ++j){ sA[j] = bf2f_bits(v0[j]); accA[j] = sA[j]; }
    float sB0 = bf2f_bits((short)(u0 & 0xffff));
    float sB1 = bf2f_bits((short)(u0 >> 16));
    accB0 = sB0; accB1 = sB1;
    logits(sA, sB0, sB1, lsA, lsB);
  }

  // independent per-edge accumulation
  auto upd1 = [&](const float* yA, float yB0, float yB1){
    float lA, lB;
    logits(yA, yB0, yB1, lA, lB);
    float pA = __expf(fminf(lA - lsA, 60.f));
    float pB = __expf(fminf(lB - lsB, 60.f));
    denA += pA; denB += pB;
#pragma unroll
    for (int j = 0; j < 8; ++j) accA[j] = fmaf(pA, yA[j], accA[j]);
    accB0 = fmaf(pB, yB0, accB0);
    accB1 = fmaf(pB, yB1, accB1);
  };

  int p = r0;
  for (; p + 3 < r1; p += 4){
    int s0i = srcg[p], s1i = srcg[p + 1], s2i = srcg[p + 2], s3i = srcg[p + 3];
    const bf16* q0 = xl + (size_t)s0i * HID;
    const bf16* q1 = xl + (size_t)s1i * HID;
    const bf16* q2 = xl + (size_t)s2i * HID;
    const bf16* q3 = xl + (size_t)s3i * HID;
    // issue all 8 row loads before any compute (hide gather latency)
    bf16x8 w0 = *(const bf16x8*)(q0 + 8 * lane);
    bf16x8 w1 = *(const bf16x8*)(q1 + 8 * lane);
    bf16x8 w2 = *(const bf16x8*)(q2 + 8 * lane);
    bf16x8 w3 = *(const bf16x8*)(q3 + 8 * lane);
    unsigned t0 = *(const unsigned*)(q0 + 512 + 2 * lane);
    unsigned t1 = *(const unsigned*)(q1 + 512 + 2 * lane);
    unsigned t2 = *(const unsigned*)(q2 + 512 + 2 * lane);
    unsigned t3 = *(const unsigned*)(q3 + 512 + 2 * lane);
    {
      float yA0[8];
#pragma unroll
      for (int j = 0; j < 8; ++j) yA0[j] = bf2f_bits(w0[j]);
      upd1(yA0, bf2f_bits((short)(t0 & 0xffff)), bf2f_bits((short)(t0 >> 16)));
    }
    {
      float yA1[8];
#pragma unroll
      for (int j = 0; j < 8; ++j) yA1[j] = bf2f_bits(w1[j]);
      upd1(yA1, bf2f_bits((short)(t1 & 0xffff)), bf2f_bits((short)(t1 >> 16)));
    }
    {
      float yA2[8];
#pragma unroll
      for (int j = 0; j < 8; ++j) yA2[j] = bf2f_bits(w2[j]);
      upd1(yA2, bf2f_bits((short)(t2 & 0xffff)), bf2f_bits((short)(t2 >> 16)));
    }
    {
      float yA3[8];
#pragma unroll
      for (int j = 0; j < 8; ++j) yA3[j] = bf2f_bits(w3[j]);
      upd1(yA3, bf2f_bits((short)(t3 & 0xffff)), bf2f_bits((short)(t3 >> 16)));
    }
  }
  for (; p < r1; ++p){
    int si = srcg[p];
    const bf16* q0 = xl + (size_t)si * HID;
    bf16x8 w0 = *(const bf16x8*)(q0 + 8 * lane);
    unsigned t0 = *(const unsigned*)(q0 + 512 + 2 * lane);
    float yA0[8];
#pragma unroll
    for (int j = 0; j < 8; ++j) yA0[j] = bf2f_bits(w0[j]);
    upd1(yA0, bf2f_bits((short)(t0 & 0xffff)), bf2f_bits((short)(t0 >> 16)));
  }

  float invA = 1.f / denA, invB = 1.f / denB;
  float4 bA0 = *(const float4*)(bias + 8 * lane);
  float4 bA1 = *(const float4*)(bias + 8 * lane + 4);
  float2 bB  = *(const float2*)(bias + 512 + 2 * lane);
  float bAa[8] = {bA0.x, bA0.y, bA0.z, bA0.w, bA1.x, bA1.y, bA1.z, bA1.w};
  bf16x8 oA;
#pragma unroll
  for (int j = 0; j < 8; ++j){
    float v = accA[j] * invA + bAa[j];
    v = v > 0.f ? v : (__expf(v) - 1.f);              // ELU
    oA[j] = f2bf_bits(v);
  }
  float vb0 = accB0 * invB + bB.x; vb0 = vb0 > 0.f ? vb0 : (__expf(vb0) - 1.f);
  float vb1 = accB1 * invB + bB.y; vb1 = vb1 > 0.f ? vb1 : (__expf(vb1) - 1.f);
  bf16* hn = H + (size_t)n * HID;
  *(bf16x8*)(hn + 8 * lane) = oA;
  unsigned ob = (unsigned)(unsigned short)f2bf_bits(vb0) |
                ((unsigned)(unsigned short)f2bf_bits(vb1) << 16);
  *(unsigned*)(hn + 512 + 2 * lane) = ob;
}

// ---------------------------------------------------------------- GAT2 fused (1 head, full-wave logit reduce)
// Fixed-reference softmax (see gat1): p = exp(l - l_self), clamp 60.
__global__ __launch_bounds__(256) void gat2_fused(const bf16* __restrict__ xl,
                                                  const bf16* __restrict__ xr,
                                                  const int* __restrict__ srcg,
                                                  const int* __restrict__ rowp,
                                                  const float* __restrict__ att,
                                                  const float* __restrict__ bias,
                                                  bf16* __restrict__ H){
  int n    = (blockIdx.x * 256 + threadIdx.x) >> 6;
  int lane = threadIdx.x & 63;
  if (n >= N_NODES) return;
  int r0 = rowp[n], r1 = rowp[n + 1];

  float4 aA0 = *(const float4*)(att + 8 * lane);
  float4 aA1 = *(const float4*)(att + 8 * lane + 4);
  float2 aBv = *(const float2*)(att + 512 + 2 * lane);
  float attA[8] = {aA0.x, aA0.y, aA0.z, aA0.w, aA1.x, aA1.y, aA1.z, aA1.w};
  float attB0 = aBv.x, attB1 = aBv.y;

  const bf16* xrn = xr + (size_t)n * HID;
  bf16x8 vr = *(const bf16x8*)(xrn + 8 * lane);
  unsigned ur = *(const unsigned*)(xrn + 512 + 2 * lane);
  float xrA[8];
#pragma unroll
  for (int j = 0; j < 8; ++j) xrA[j] = bf2f_bits(vr[j]);
  float xrB0 = bf2f_bits((short)(ur & 0xffff));
  float xrB1 = bf2f_bits((short)(ur >> 16));

  auto logit1 = [&](const float* xA, float xB0, float xB1)->float{
    float s0 = xB0 + xrB0; s0 *= (s0 > 0.f) ? 1.f : NEG_SLOPE;
    float s1 = xB1 + xrB1; s1 *= (s1 > 0.f) ? 1.f : NEG_SLOPE;
    float pa = attB0 * s0 + attB1 * s1;
#pragma unroll
    for (int j = 0; j < 8; ++j){
      float s = xA[j] + xrA[j];
      s *= (s > 0.f) ? 1.f : NEG_SLOPE;
      pa = fmaf(attA[j], s, pa);
    }
    pa += __shfl_xor(pa, 1);
    pa += __shfl_xor(pa, 2);
    pa += __shfl_xor(pa, 4);
    pa += __shfl_xor(pa, 8);
    pa += __shfl_xor(pa, 16);
    pa += __shfl_xor(pa, 32);
    return pa;
  };

  float accA[8], accB0, accB1, ls;
  float den = 1.f;
  {
    const bf16* xn = xl + (size_t)n * HID;
    bf16x8 v0 = *(const bf16x8*)(xn + 8 * lane);
    unsigned u0 = *(const unsigned*)(xn + 512 + 2 * lane);
    float sA[8];
#pragma unroll
    for (int j = 0; j < 8; ++j){ sA[j] = bf2f_bits(v0[j]); accA[j] = sA[j]; }
    float sB0 = bf2f_bits((short)(u0 & 0xffff));
    float sB1 = bf2f_bits((short)(u0 >> 16));
    accB0 = sB0; accB1 = sB1;
    ls = logit1(sA, sB0, sB1);
  }

  auto upd1 = [&](const float* yA, float yB0, float yB1){
    float l = logit1(yA, yB0, yB1);
    float pv = __expf(fminf(l - ls, 60.f));
    den += pv;
#pragma unroll
    for (int j = 0; j < 8; ++j) accA[j] = fmaf(pv, yA[j], accA[j]);
    accB0 = fmaf(pv, yB0, accB0);
    accB1 = fmaf(pv, yB1, accB1);
  };

  int p = r0;
  for (; p + 3 < r1; p += 4){
    int s0i = srcg[p], s1i = srcg[p + 1], s2i = srcg[p + 2], s3i = srcg[p + 3];
    const bf16* q0 = xl + (size_t)s0i * HID;
    const bf16* q1 = xl + (size_t)s1i * HID;
    const bf16* q2 = xl + (size_t)s2i * HID;
    const bf16* q3 = xl + (size_t)s3i * HID;
    bf16x8 w0 = *(const bf16x8*)(q0 + 8 * lane);
    bf16x8 w1 = *(const bf16x8*)(q1 + 8 * lane);
    bf16x8 w2 = *(const bf16x8*)(q2 + 8 * lane);
    bf16x8 w3 = *(const bf16x8*)(q3 + 8 * lane);
    unsigned t0 = *(const unsigned*)(q0 + 512 + 2 * lane);
    unsigned t1 = *(const unsigned*)(q1 + 512 + 2 * lane);
    unsigned t2 = *(const unsigned*)(q2 + 512 + 2 * lane);
    unsigned t3 = *(const unsigned*)(q3 + 512 + 2 * lane);
    {
      float yA0[8];
#pragma unroll
      for (int j = 0; j < 8; ++j) yA0[j] = bf2f_bits(w0[j]);
      upd1(yA0, bf2f_bits((short)(t0 & 0xffff)), bf2f_bits((short)(t0 >> 16)));
    }
    {
      float yA1[8];
#pragma unroll
      for (int j = 0; j < 8; ++j) yA1[j] = bf2f_bits(w1[j]);
      upd1(yA1, bf2f_bits((short)(t1 & 0xffff)), bf2f_bits((short)(t1 >> 16)));
    }
    {
      float yA2[8];
#pragma unroll
      for (int j = 0; j < 8; ++j) yA2[j] = bf2f_bits(w2[j]);
      upd1(yA2, bf2f_bits((short)(t2 & 0xffff)), bf2f_bits((short)(t2 >> 16)));
    }
    {
      float yA3[8];
#pragma unroll
      for (int j = 0; j < 8; ++j) yA3[j] = bf2f_bits(w3[j]);
      upd1(yA3, bf2f_bits((short)(t3 & 0xffff)), bf2f_bits((short)(t3 >> 16)));
    }
  }
  for (; p < r1; ++p){
    int si = srcg[p];
    const bf16* q0 = xl + (size_t)si * HID;
    bf16x8 w0 = *(const bf16x8*)(q0 + 8 * lane);
    unsigned t0 = *(const unsigned*)(q0 + 512 + 2 * lane);
    float yA0[8];
#pragma unroll
    for (int j = 0; j < 8; ++j) yA0[j] = bf2f_bits(w0[j]);
    upd1(yA0, bf2f_bits((short)(t0 & 0xffff)), bf2f_bits((short)(t0 >> 16)));
  }

  float inv = 1.f / den;
  float4 bA0 = *(const float4*)(bias + 8 * lane);
  float4 bA1 = *(const float4*)(bias + 8 * lane + 4);
  float2 bB  = *(const float2*)(bias + 512 + 2 * lane);
  float bAa[8] = {bA0.x, bA0.y, bA0.z, bA0.w, bA1.x, bA1.y, bA1.z, bA1.w};
  bf16x8 oA;
#pragma unroll
  for (int j = 0; j < 8; ++j) oA[j] = f2bf_bits(accA[j] * inv + bAa[j]);
  bf16* hn = H + (size_t)n * HID;
  *(bf16x8*)(hn + 8 * lane) = oA;
  unsigned ob = (unsigned)(unsigned short)f2bf_bits(accB0 * inv + bB.x) |
                ((unsigned)(unsigned short)f2bf_bits(accB1 * inv + bB.y) << 16);
  *(unsigned*)(hn + 512 + 2 * lane) = ob;
}

// ---------------------------------------------------------------- fused GCN + pooling (block per graph)
// batch is sorted -> each graph is a contiguous node range [gstart[g], gstart[g+1]).
// 4 waves round-robin the graph's nodes; each wave computes the GCN row (bias+ReLU, f32)
// in registers and pool-accumulates (max/sum) into lane-private registers;
// one LDS reduction (4 partials) writes the 2x640 f32 output directly. No h3 roundtrip.
__global__ __launch_bounds__(256) void gcn_pool(const bf16* __restrict__ xw,
                                                const int* __restrict__ srcg,
                                                const int* __restrict__ rowp,
                                                const float* __restrict__ dinv,
                                                const float* __restrict__ bg,
                                                const int* __restrict__ gstart,
                                                float* __restrict__ out){
  __shared__ float red[8][HID];      // [0..3]=max partials, [4..7]=sum partials (20.5 KB)
  int g    = blockIdx.x;
  int n0   = gstart[g], n1 = gstart[g + 1];
  int lane = threadIdx.x & 63;
  int wv   = threadIdx.x >> 6;

  float4 bA0 = *(const float4*)(bg + 8 * lane);
  float4 bA1 = *(const float4*)(bg + 8 * lane + 4);
  float2 bB  = *(const float2*)(bg + 512 + 2 * lane);
  float bAa[8] = {bA0.x, bA0.y, bA0.z, bA0.w, bA1.x, bA1.y, bA1.z, bA1.w};

  float mxA[8] = {0.f,0.f,0.f,0.f,0.f,0.f,0.f,0.f};
  float smA[8] = {0.f,0.f,0.f,0.f,0.f,0.f,0.f,0.f};
  float mxB0 = 0.f, mxB1 = 0.f, smB0 = 0.f, smB1 = 0.f;

  for (int n = n0 + wv; n < n1; n += 4){
    int r0 = rowp[n], r1 = rowp[n + 1];
    float dn = dinv[n];
    float accA[8], accB[2];
    {
      float w = dn * dn;
      const bf16* xn = xw + (size_t)n * HID;
      bf16x8 va = *(const bf16x8*)(xn + 8 * lane);
      unsigned vb = *(const unsigned*)(xn + 512 + 2 * lane);
#pragma unroll
      for (int j = 0; j < 8; ++j) accA[j] = w * bf2f_bits(va[j]);
      accB[0] = w * bf2f_bits((short)(vb & 0xffff));
      accB[1] = w * bf2f_bits((short)(vb >> 16));
    }
    int p = r0;
    for (; p + 3 < r1; p += 4){
      int s0 = srcg[p], s1 = srcg[p + 1], s2 = srcg[p + 2], s3 = srcg[p + 3];
      const bf16* xs0 = xw + (size_t)s0 * HID;
      const bf16* xs1 = xw + (size_t)s1 * HID;
      const bf16* xs2 = xw + (size_t)s2 * HID;
      const bf16* xs3 = xw + (size_t)s3 * HID;
      float w0 = dinv[s0] * dn, w1 = dinv[s1] * dn, w2 = dinv[s2] * dn, w3 = dinv[s3] * dn;
      bf16x8 va0 = *(const bf16x8*)(xs0 + 8 * lane);
      bf16x8 va1 = *(const bf16x8*)(xs1 + 8 * lane);
      bf16x8 va2 = *(const bf16x8*)(xs2 + 8 * lane);
      bf16x8 va3 = *(const bf16x8*)(xs3 + 8 * lane);
      unsigned vb0 = *(const unsigned*)(xs0 + 512 + 2 * lane);
      unsigned vb1 = *(const unsigned*)(xs1 + 512 + 2 * lane);
      unsigned vb2 = *(const unsigned*)(xs2 + 512 + 2 * lane);
      unsigned vb3 = *(const unsigned*)(xs3 + 512 + 2 * lane);
#pragma unroll
      for (int j = 0; j < 8; ++j)
        accA[j] += w0 * bf2f_bits(va0[j]) + w1 * bf2f_bits(va1[j])
                 + w2 * bf2f_bits(va2[j]) + w3 * bf2f_bits(va3[j]);
      accB[0] += w0 * bf2f_bits((short)(vb0 & 0xffff)) + w1 * bf2f_bits((short)(vb1 & 0xffff))
               + w2 * bf2f_bits((short)(vb2 & 0xffff)) + w3 * bf2f_bits((short)(vb3 & 0xffff));
      accB[1] += w0 * bf2f_bits((short)(vb0 >> 16))    + w1 * bf2f_bits((short)(vb1 >> 16))
               + w2 * bf2f_bits((short)(vb2 >> 16))    + w3 * bf2f_bits((short)(vb3 >> 16));
    }
    for (; p < r1; ++p){
      int s = srcg[p];
      float w = dinv[s] * dn;
      const bf16* xs = xw + (size_t)s * HID;
      bf16x8 va = *(const bf16x8*)(xs + 8 * lane);
      unsigned vb = *(const unsigned*)(xs + 512 + 2 * lane);
#pragma unroll
      for (int j = 0; j < 8; ++j) accA[j] += w * bf2f_bits(va[j]);
      accB[0] += w * bf2f_bits((short)(vb & 0xffff));
      accB[1] += w * bf2f_bits((short)(vb >> 16));
    }
    // bias + ReLU (f32), then pool-accumulate
#pragma unroll
    for (int j = 0; j < 8; ++j){
      float v = fmaxf(accA[j] + bAa[j], 0.f);
      mxA[j] = fmaxf(mxA[j], v); smA[j] += v;
    }
    {
      float v0 = fmaxf(accB[0] + bB.x, 0.f);
      float v1 = fmaxf(accB[1] + bB.y, 0.f);
      mxB0 = fmaxf(mxB0, v0); smB0 += v0;
      mxB1 = fmaxf(mxB1, v1); smB1 += v1;
    }
  }

  // per-wave partials -> LDS
#pragma unroll
  for (int j = 0; j < 8; ++j){
    red[wv][8 * lane + j]     = mxA[j];
    red[4 + wv][8 * lane + j] = smA[j];
  }
  red[wv][512 + 2 * lane]         = mxB0;
  red[wv][512 + 2 * lane + 1]     = mxB1;
  red[4 + wv][512 + 2 * lane]     = smB0;
  red[4 + wv][512 + 2 * lane + 1] = smB1;
  __syncthreads();

  float inv = (n1 > n0) ? 1.f / (float)(n1 - n0) : 0.f;
  float* og = out + (size_t)g * 2 * HID;
  for (int c = threadIdx.x; c < HID; c += 256){
    float mx = fmaxf(fmaxf(red[0][c], red[1][c]), fmaxf(red[2][c], red[3][c]));
    float sm = red[4][c] + red[5][c] + red[6][c] + red[7][c];
    og[c]       = mx;
    og[HID + c] = sm * inv;
  }
}

// ---------------------------------------------------------------- per-graph bounds (batch is sorted)
__global__ __launch_bounds__(256) void graph_bounds(const int* __restrict__ batch,
                                                    int* __restrict__ gstart){
  int n = blockIdx.x * 256 + threadIdx.x;
  if (n >= N_NODES) return;
  int b = clampi(batch[n], N_GRAPHS);
  if (n == 0){
    for (int g = 0; g <= b; ++g) gstart[g] = 0;
  } else {
    int bp = clampi(batch[n - 1], N_GRAPHS);
    for (int g = bp + 1; g <= b; ++g) gstart[g] = n;
  }
  if (n == N_NODES - 1){
    for (int g = b + 1; g <= N_GRAPHS; ++g) gstart[g] = N_NODES;
  }
}

// ---------------------------------------------------------------- launch
extern "C" void kernel_launch(void* const* d_in, const int* in_sizes, int n_in,
                              void* d_out, int out_size, void* d_ws, size_t ws_size,
                              hipStream_t stream){
  const float* x     = (const float*)d_in[0];
  const int*   ei    = (const int*)d_in[1];
  const int*   batch = (const int*)d_in[2];
  const float* Wl1 = (const float*)d_in[3];
  const float* Wr1 = (const float*)d_in[4];
  const float* a1  = (const float*)d_in[5];
  const float* b1  = (const float*)d_in[6];
  const float* Wl2 = (const float*)d_in[7];
  const float* Wr2 = (const float*)d_in[8];
  const float* a2  = (const float*)d_in[9];
  const float* b2  = (const float*)d_in[10];
  const float* Wg  = (const float*)d_in[11];
  const float* bg  = (const float*)d_in[12];
  const int* esrc = ei;
  const int* edst = ei + N_EDGES;

  // ---- workspace layout ----
  char* ws = (char*)d_ws;
  size_t off = 0;
  auto take = [&](size_t bytes)->char*{
    char* p = ws + off; off = (off + bytes + 255) & ~(size_t)255; return p;
  };
  bf16*     X1   = (bf16*)    take((size_t)N_NODES * HID * 2);
  bf16*     X2   = (bf16*)    take((size_t)N_NODES * HID * 2);
  bf16*     H    = (bf16*)    take((size_t)N_NODES * HID * 2);
  bf16*     XB   = (bf16*)    take((size_t)N_NODES * K1P * 2);
  // WT1l|WT1r contiguous (one 1280xK1P matrix); WT2l|WT2r|WTg contiguous.
  bf16*     WT1l = (bf16*)    take((size_t)HID * K1P * 2);
  bf16*     WT1r = (bf16*)    take((size_t)HID * K1P * 2);
  bf16*     WT2l = (bf16*)    take((size_t)HID * HID * 2);
  bf16*     WT2r = (bf16*)    take((size_t)HID * HID * 2);
  bf16*     WTg  = (bf16*)    take((size_t)HID * HID * 2);
  int*      DEGI = (int*)     take((size_t)N_NODES * 4);
  int*      ROWP = (int*)     take((size_t)(N_NODES + 1) * 4);
  int*      CURS = (int*)     take((size_t)N_NODES * 4);
  int*      SRCG = (int*)     take((size_t)N_EDGES * 4);
  int*      DSTG = (int*)     take((size_t)N_EDGES * 4);
  float*    DINV = (float*)   take((size_t)N_NODES * 4);
  int*      GST  = (int*)     take((size_t)(N_GRAPHS + 1) * 4);
  int*      BSUM = (int*)     take((size_t)SCB * 4);
  (void)WT1r; (void)WT2r; (void)DSTG; (void)X2;

  dim3 blk(256);
  auto fill = [&](void* p, unsigned v, int n){
    fill_u32<<<dim3((n + 255) / 256), blk, 0, stream>>>((unsigned*)p, v, n);
  };
  const int MB8     = ((N_NODES + BM - 1) / BM + 7) / 8;   // 128-row strips per XCD (49)
  const int nblocks = (N_NODES * 64 + 255) / 256;
  const int reblk   = (N_EDGES + 255) / 256;

  // ---- prep + CSR ----
  conv_x<<<(N_NODES * K1P + 255) / 256, blk, 0, stream>>>(x, XB);
  conv_wT2<<<(2 * HID * K1P + 255) / 256, blk, 0, stream>>>(Wl1, Wr1, WT1l, IN_DIM, HID, K1P);
  conv_wT3t<<<dim3(HID / 32, HID / 32, 3), blk, 0, stream>>>(Wl2, Wr2, Wg, WT2l);
  fill(DEGI, 0u, N_NODES);
  count_deg<<<reblk, blk, 0, stream>>>(edst, DEGI);
  scan_blk<<<dim3(SCB), blk, 0, stream>>>(DEGI, ROWP, DINV, BSUM);
  scan_top<<<dim3(1), blk, 0, stream>>>(BSUM, ROWP);
  scan_add<<<dim3(SCB), blk, 0, stream>>>(BSUM, ROWP, CURS);
  bucket_edges<<<reblk, blk, 0, stream>>>(esrc, edst, CURS, SRCG, DSTG);
  graph_bounds<<<(N_NODES + 255) / 256, blk, 0, stream>>>(batch, GST);

  // ---- GATv2 layer 1 (merged Wl|Wr GEMM, N=1280; fused logits+agg) ----
  mfma_gemm<<<dim3(8 * MB8 * 10), blk, 0, stream>>>(XB, WT1l, X1, X2, N_NODES, K1P, 10);
  gat1_fused<<<nblocks, blk, 0, stream>>>(X1, X2, SRCG, ROWP, a1, b1, H);

  // ---- GATv2 layer 2 (merged Wl|Wr GEMM, N=1280; fused logits+agg) ----
  mfma_gemm<<<dim3(8 * MB8 * 10), blk, 0, stream>>>(H, WT2l, X1, X2, N_NODES, HID, 10);
  gat2_fused<<<nblocks, blk, 0, stream>>>(X1, X2, SRCG, ROWP, a2, b2, H);

  // ---- GCN GEMM + fused gather/pool (no h3 roundtrip) ----
  mfma_gemm<<<dim3(8 * MB8 * 5), blk, 0, stream>>>(H, WTg, X1, X1, N_NODES, HID, 5);
  gcn_pool<<<dim3(N_GRAPHS), blk, 0, stream>>>(X1, SRCG, ROWP, DINV, bg, GST, (float*)d_out);
}